// Round 1
// baseline (884.037 us; speedup 1.0000x reference)
//
#include <hip/hip_runtime.h>
#include <math.h>

#define L_SEQ 1024
#define DMODEL 512
#define NHEAD 8
#define NB 2
#define INV_TEMP 0.125f

// ---------------------------------------------------------------------------
// Generic 64x64 tiled fp32 GEMM body: C[m,n] = sum_k A[m,k]*B[k,n] (+bias[n])
// 256 threads, 4x4 micro-tile per thread, TK=16.
// Requires M%64==0, N tile fully in range, K%16==0 (true for all our shapes).
// ---------------------------------------------------------------------------
__device__ __forceinline__ void gemm_body(
    const float* __restrict__ A, int lda,
    const float* __restrict__ B, int ldb,
    const float* __restrict__ bias,
    float* __restrict__ C, int ldc,
    int K, int m0, int n0)
{
    __shared__ float As[16][68];   // [k][m], padded: row stride 68 floats (16B aligned)
    __shared__ float Bs[16][68];   // [k][n]
    const int t  = threadIdx.x;
    const int tx = t & 15, ty = t >> 4;
    const int am = t >> 2, ak = (t & 3) << 2;   // A-load coords: 64 m x 16 k
    const int bk = t >> 4, bn = (t & 15) << 2;  // B-load coords: 16 k x 64 n
    float acc[4][4] = {};

    for (int k0 = 0; k0 < K; k0 += 16) {
        float4 av = *(const float4*)&A[(size_t)(m0 + am) * lda + k0 + ak];
        float4 bv = *(const float4*)&B[(size_t)(k0 + bk) * ldb + n0 + bn];
        __syncthreads();            // protect previous iteration's LDS reads
        As[ak + 0][am] = av.x;
        As[ak + 1][am] = av.y;
        As[ak + 2][am] = av.z;
        As[ak + 3][am] = av.w;
        *(float4*)&Bs[bk][bn] = bv;
        __syncthreads();
#pragma unroll
        for (int kk = 0; kk < 16; ++kk) {
            float4 a4 = *(float4*)&As[kk][ty << 2];
            float4 b4 = *(float4*)&Bs[kk][tx << 2];
            float ar[4] = {a4.x, a4.y, a4.z, a4.w};
            float br[4] = {b4.x, b4.y, b4.z, b4.w};
#pragma unroll
            for (int i = 0; i < 4; ++i)
#pragma unroll
                for (int j = 0; j < 4; ++j)
                    acc[i][j] += ar[i] * br[j];
        }
    }

    float4 bsv = {0.f, 0.f, 0.f, 0.f};
    if (bias) bsv = *(const float4*)&bias[n0 + (tx << 2)];
#pragma unroll
    for (int i = 0; i < 4; ++i) {
        float4 o;
        o.x = acc[i][0] + bsv.x;
        o.y = acc[i][1] + bsv.y;
        o.z = acc[i][2] + bsv.z;
        o.w = acc[i][3] + bsv.w;
        *(float4*)&C[(size_t)(m0 + (ty << 2) + i) * ldc + n0 + (tx << 2)] = o;
    }
}

// C = A(MxK) * B(KxN) + bias, all row-major contiguous (lda=K, ldb=ldc=N)
__global__ __launch_bounds__(256) void gemm_bias_kernel(
    const float* __restrict__ A, const float* __restrict__ B,
    const float* __restrict__ bias, float* __restrict__ C,
    int N, int K)
{
    gemm_body(A, K, B, N, bias, C, N, K, blockIdx.y * 64, blockIdx.x * 64);
}

// out[b,l,h*64+d] = sum_m attn[(h*2+b), l, m] * vh[b, m, h*64+d]
__global__ __launch_bounds__(256) void gemm_av_kernel(
    const float* __restrict__ attn, const float* __restrict__ vh,
    float* __restrict__ outv)
{
    const int z = blockIdx.z;          // z = h*2 + b
    const int h = z >> 1, b = z & 1;
    const float* A = attn + (size_t)z * L_SEQ * L_SEQ;                 // lda = 1024
    const float* B = vh + (size_t)b * L_SEQ * DMODEL + h * 64;         // ldb = 512
    float*       C = outv + (size_t)b * L_SEQ * DMODEL + h * 64;       // ldc = 512
    gemm_body(A, L_SEQ, B, DMODEL, nullptr, C, DMODEL, L_SEQ, blockIdx.y * 64, 0);
}

// ---------------------------------------------------------------------------
// Scores + tf-bias + mask + softmax, one block per (b, l), all 8 heads.
// Writes normalized attention [h*2+b][l][m] to global.
// ---------------------------------------------------------------------------
__global__ __launch_bounds__(256) void scores_softmax_kernel(
    const float* __restrict__ qh, const float* __restrict__ kh,
    const int* __restrict__ mask,
    const int* __restrict__ tf1, const int* __restrict__ tf2,
    const int* __restrict__ tf3, const int* __restrict__ tf4,
    const int* __restrict__ tf5,
    const float* __restrict__ emb1, const float* __restrict__ emb2,
    const float* __restrict__ emb3, const float* __restrict__ emb4,
    const float* __restrict__ emb5,
    float* __restrict__ attn)
{
    const int l = blockIdx.x;
    const int b = blockIdx.y;
    const int t = threadIdx.x;

    __shared__ float qs[DMODEL];            // q row, all heads
    __shared__ float embs[5][NHEAD][64];    // transposed emb tables: [feat][h][idx]
    __shared__ float s[NHEAD][L_SEQ];       // score rows (32 KB)
    __shared__ float rinv[NHEAD];

    // stage q row (coalesced float4)
    {
        const float4* qsrc = (const float4*)(qh + ((size_t)(b * L_SEQ + l)) * DMODEL);
        float4* qd = (float4*)qs;
        for (int i = t; i < DMODEL / 4; i += 256) qd[i] = qsrc[i];
    }
    // stage emb tables transposed: embs[j][h][i] = embj[i*8+h]
    {
        const float* es[5] = {emb1, emb2, emb3, emb4, emb5};
        for (int i = t; i < 5 * 512; i += 256) {
            int j = i >> 9, rem = i & 511;
            int h = rem >> 6, idx = rem & 63;
            embs[j][h][idx] = es[j][idx * NHEAD + h];
        }
    }
    __syncthreads();

    const size_t rowbase = ((size_t)(b * L_SEQ + l)) * L_SEQ;
    const float4* q4 = (const float4*)qs;

    for (int c = 0; c < 4; ++c) {
        const int m = (c << 8) + t;
        const int am  = mask[rowbase + m];
        const int t1v = tf1[rowbase + m];
        float acc[NHEAD];
        if (t1v >= 0) {
            const int i2 = tf2[rowbase + m];
            const int i3 = tf3[rowbase + m];
            const int i4 = tf4[rowbase + m];
            const int i5 = tf5[rowbase + m];
#pragma unroll
            for (int h = 0; h < NHEAD; ++h)
                acc[h] = embs[0][h][t1v] + embs[1][h][i2] + embs[2][h][i3]
                       + embs[3][h][i4] + embs[4][h][i5];
        } else {
#pragma unroll
            for (int h = 0; h < NHEAD; ++h) acc[h] = 0.f;
        }
        const float4* kr = (const float4*)(kh + ((size_t)(b * L_SEQ + m)) * DMODEL);
#pragma unroll
        for (int h = 0; h < NHEAD; ++h) {
            float d0 = 0.f;
#pragma unroll
            for (int d4 = 0; d4 < 16; ++d4) {
                float4 kv = kr[h * 16 + d4];
                float4 qv = q4[h * 16 + d4];     // LDS broadcast (same addr all lanes)
                d0 += kv.x * qv.x + kv.y * qv.y + kv.z * qv.z + kv.w * qv.w;
            }
            float sc = (d0 + acc[h]) * INV_TEMP;
            s[h][m] = am ? -INFINITY : sc;
        }
    }
    __syncthreads();

    // softmax: 8 groups of 32 threads, one head each
    {
        const int h = t >> 5, i = t & 31;
        float mx = -INFINITY;
        for (int m = i; m < L_SEQ; m += 32) mx = fmaxf(mx, s[h][m]);
#pragma unroll
        for (int off = 16; off; off >>= 1) mx = fmaxf(mx, __shfl_down(mx, off, 32));
        mx = __shfl(mx, 0, 32);
        float sm = 0.f;
        for (int m = i; m < L_SEQ; m += 32) {
            float e = __expf(s[h][m] - mx);
            s[h][m] = e;
            sm += e;
        }
#pragma unroll
        for (int off = 16; off; off >>= 1) sm += __shfl_down(sm, off, 32);
        if (i == 0) rinv[h] = 1.0f / sm;
    }
    __syncthreads();

    float inv[NHEAD];
#pragma unroll
    for (int h = 0; h < NHEAD; ++h) inv[h] = rinv[h];
    for (int m = t; m < L_SEQ; m += 256) {
#pragma unroll
        for (int h = 0; h < NHEAD; ++h) {
            attn[(((size_t)(h * NB + b)) * L_SEQ + l) * L_SEQ + m] = s[h][m] * inv[h];
        }
    }
}

// ---------------------------------------------------------------------------
// residual add + LayerNorm, one block per row
// ---------------------------------------------------------------------------
__global__ __launch_bounds__(256) void ln_kernel(
    const float* __restrict__ x, const float* __restrict__ res,
    const float* __restrict__ g, const float* __restrict__ bvec,
    float* __restrict__ out)
{
    const int row = blockIdx.x;
    const int t = threadIdx.x;
    float2 xv = ((const float2*)(x + (size_t)row * DMODEL))[t];
    float2 rv = ((const float2*)(res + (size_t)row * DMODEL))[t];
    const float a = xv.x + rv.x;
    const float c = xv.y + rv.y;
    float s = a + c, sq = a * a + c * c;
#pragma unroll
    for (int off = 32; off; off >>= 1) {
        s  += __shfl_down(s, off);
        sq += __shfl_down(sq, off);
    }
    __shared__ float ssum[4], ssq[4];
    __shared__ float smu, srs;
    const int wid = t >> 6, lane = t & 63;
    if (lane == 0) { ssum[wid] = s; ssq[wid] = sq; }
    __syncthreads();
    if (t == 0) {
        float ts = ssum[0] + ssum[1] + ssum[2] + ssum[3];
        float tq = ssq[0] + ssq[1] + ssq[2] + ssq[3];
        float mu = ts * (1.0f / DMODEL);
        float var = tq * (1.0f / DMODEL) - mu * mu;
        smu = mu;
        srs = rsqrtf(var + 1e-5f);
    }
    __syncthreads();
    const float mu = smu, rs = srs;
    float2 gv = ((const float2*)g)[t];
    float2 bv = ((const float2*)bvec)[t];
    float2 o;
    o.x = (a - mu) * rs * gv.x + bv.x;
    o.y = (c - mu) * rs * gv.y + bv.y;
    ((float2*)(out + (size_t)row * DMODEL))[t] = o;
}

extern "C" void kernel_launch(void* const* d_in, const int* in_sizes, int n_in,
                              void* d_out, int out_size, void* d_ws, size_t ws_size,
                              hipStream_t stream)
{
    const float* q    = (const float*)d_in[0];
    const float* k    = (const float*)d_in[1];
    const float* v    = (const float*)d_in[2];
    const int*   mask = (const int*)d_in[3];
    const int*   tf1  = (const int*)d_in[4];
    const int*   tf2  = (const int*)d_in[5];
    const int*   tf3  = (const int*)d_in[6];
    const int*   tf4  = (const int*)d_in[7];
    const int*   tf5  = (const int*)d_in[8];
    const float* w_q  = (const float*)d_in[9];
    const float* b_q  = (const float*)d_in[10];
    const float* w_k  = (const float*)d_in[11];
    const float* b_k  = (const float*)d_in[12];
    const float* w_v  = (const float*)d_in[13];
    const float* b_v  = (const float*)d_in[14];
    const float* emb1 = (const float*)d_in[15];
    const float* emb2 = (const float*)d_in[16];
    const float* emb3 = (const float*)d_in[17];
    const float* emb4 = (const float*)d_in[18];
    const float* emb5 = (const float*)d_in[19];
    const float* fc_w = (const float*)d_in[20];
    const float* fc_b = (const float*)d_in[21];
    const float* ln_g = (const float*)d_in[22];
    const float* ln_b = (const float*)d_in[23];

    float* out  = (float*)d_out;                       // [2048][512]
    float* attn = out + (size_t)NB * L_SEQ * DMODEL;   // [16][1024][1024]

    float* qh  = (float*)d_ws;                         // each 1 Mi floats (4 MB)
    float* kh  = qh + 1048576;
    float* vh  = kh + 1048576;
    float* pv  = vh + 1048576;                         // attn @ V
    float* fco = pv + 1048576;                         // fc output

    const int M = NB * L_SEQ;                          // 2048
    dim3 gproj(DMODEL / 64, M / 64);                   // (8, 32)

    gemm_bias_kernel<<<gproj, 256, 0, stream>>>(q, w_q, b_q, qh, DMODEL, DMODEL);
    gemm_bias_kernel<<<gproj, 256, 0, stream>>>(k, w_k, b_k, kh, DMODEL, DMODEL);
    gemm_bias_kernel<<<gproj, 256, 0, stream>>>(v, w_v, b_v, vh, DMODEL, DMODEL);

    scores_softmax_kernel<<<dim3(L_SEQ, NB), 256, 0, stream>>>(
        qh, kh, mask, tf1, tf2, tf3, tf4, tf5,
        emb1, emb2, emb3, emb4, emb5, attn);

    gemm_av_kernel<<<dim3(1, L_SEQ / 64, NHEAD * NB), 256, 0, stream>>>(attn, vh, pv);

    gemm_bias_kernel<<<gproj, 256, 0, stream>>>(pv, fc_w, fc_b, fco, DMODEL, DMODEL);

    ln_kernel<<<M, 256, 0, stream>>>(fco, q, ln_g, ln_b, out);
}

// Round 2
// 335.866 us; speedup vs baseline: 2.6321x; 2.6321x over previous
//
#include <hip/hip_runtime.h>
#include <math.h>

#define L_SEQ 1024
#define DMODEL 512
#define NHEAD 8
#define NB 2

typedef __attribute__((ext_vector_type(8))) short bf8;
typedef __attribute__((ext_vector_type(4))) float f4;

__device__ __forceinline__ short f2bf(float f) {
    unsigned u = __float_as_uint(f);
    unsigned r = u + 0x7FFF + ((u >> 16) & 1);   // round-to-nearest-even
    return (short)(r >> 16);
}

// ---------------------------------------------------------------------------
// fp32 -> bf16 cast, vectorized
// ---------------------------------------------------------------------------
__global__ __launch_bounds__(256) void cast_bf16_kernel(
    const float* __restrict__ src, short* __restrict__ dst, int n4)
{
    int i = blockIdx.x * 256 + threadIdx.x;
    if (i < n4) {
        float4 f = ((const float4*)src)[i];
        short4 o;
        o.x = f2bf(f.x); o.y = f2bf(f.y); o.z = f2bf(f.z); o.w = f2bf(f.w);
        ((short4*)dst)[i] = o;
    }
}

// ---------------------------------------------------------------------------
// 512x512 fp32 W[k][n] -> bf16 Wt[n][k], 4 matrices via blockIdx.z
// ---------------------------------------------------------------------------
__global__ __launch_bounds__(256) void transpose_cast_kernel(
    const float* __restrict__ s0, const float* __restrict__ s1,
    const float* __restrict__ s2, const float* __restrict__ s3,
    short* __restrict__ d0, short* __restrict__ d1,
    short* __restrict__ d2, short* __restrict__ d3)
{
    const float* src; short* dst;
    switch (blockIdx.z) {
        case 0: src = s0; dst = d0; break;
        case 1: src = s1; dst = d1; break;
        case 2: src = s2; dst = d2; break;
        default: src = s3; dst = d3; break;
    }
    __shared__ float tile[32][33];
    const int tx = threadIdx.x, ty = threadIdx.y;
    const int x0 = blockIdx.x * 32, y0 = blockIdx.y * 32;
#pragma unroll
    for (int j = 0; j < 32; j += 8)
        tile[ty + j][tx] = src[(size_t)(y0 + ty + j) * 512 + x0 + tx];
    __syncthreads();
#pragma unroll
    for (int j = 0; j < 32; j += 8)
        dst[(size_t)(x0 + ty + j) * 512 + y0 + tx] = f2bf(tile[tx][ty + j]);
}

// ---------------------------------------------------------------------------
// MFMA GEMM: C[m,n] = sum_k A[m,k]*Bt[n,k] + bias[n]
// A bf16 [2048 x 512] row-major, Bt bf16 [512 x 512] (pre-transposed weights).
// Block = 256 thr = 4 waves; tile 64m x 64n; wave w owns rows m_base+w*16..+15,
// all 64 n via 4 MFMA n-frags. K-loop 16 iters of 32.
// MODE 0: bf16 natural [m][n]; MODE 1: bf16 transposed vht[b][n][l] (m=b*1024+l);
// MODE 2: fp32 natural.
// ---------------------------------------------------------------------------
template<int MODE>
__global__ __launch_bounds__(256) void gemm_mfma_kernel(
    const short* __restrict__ A, const short* __restrict__ Bt,
    const float* __restrict__ bias, void* __restrict__ Cout)
{
    const int w = threadIdx.x >> 6, lane = threadIdx.x & 63;
    const int lr = lane & 15, lq = lane >> 4;
    const int m_base = blockIdx.y * 64 + w * 16;
    const int n_base = blockIdx.x * 64;

    f4 acc[4];
    const f4 zero = {0.f, 0.f, 0.f, 0.f};
#pragma unroll
    for (int nf = 0; nf < 4; ++nf) acc[nf] = zero;

    for (int k0 = 0; k0 < 512; k0 += 32) {
        bf8 a = *(const bf8*)(A + (size_t)(m_base + lr) * 512 + k0 + lq * 8);
#pragma unroll
        for (int nf = 0; nf < 4; ++nf) {
            bf8 b = *(const bf8*)(Bt + (size_t)(n_base + nf * 16 + lr) * 512 + k0 + lq * 8);
            acc[nf] = __builtin_amdgcn_mfma_f32_16x16x32_bf16(a, b, acc[nf], 0, 0, 0);
        }
    }

#pragma unroll
    for (int nf = 0; nf < 4; ++nf) {
        const int n = n_base + nf * 16 + lr;
        const float bv = bias[n];
        const int mrow = m_base + lq * 4;
#pragma unroll
        for (int r = 0; r < 4; ++r) {
            const float val = acc[nf][r] + bv;
            const int m = mrow + r;
            if (MODE == 0) {
                ((short*)Cout)[(size_t)m * 512 + n] = f2bf(val);
            } else if (MODE == 1) {
                const int bb = m >> 10, l = m & 1023;
                ((short*)Cout)[((size_t)bb * 512 + n) * 1024 + l] = f2bf(val);
            } else {
                ((float*)Cout)[(size_t)m * 512 + n] = val;
            }
        }
    }
}

// ---------------------------------------------------------------------------
// Scores GEMM: per z=h*2+b, S[l,m] = sum_d qh[b,l,h*64+d]*kh[b,m,h*64+d]
// Block 256 thr = 4 waves in 2x2; tile 128l x 128m; wave tile 64x64 = 4x4 frags.
// K=64 -> 2 MFMA k-steps, all frags preloaded, no LDS.
// Writes RAW fp32 scores (no bias/temp) to sc[z][l][m].
// ---------------------------------------------------------------------------
__global__ __launch_bounds__(256) void scores_mfma_kernel(
    const short* __restrict__ qh, const short* __restrict__ kh,
    float* __restrict__ sc)
{
    const int z = blockIdx.z, h = z >> 1, b = z & 1;
    const int w = threadIdx.x >> 6, lane = threadIdx.x & 63;
    const int wr = w >> 1, wc = w & 1;
    const int lr = lane & 15, lq = lane >> 4;
    const int l0 = blockIdx.y * 128 + wr * 64;
    const int m0 = blockIdx.x * 128 + wc * 64;
    const int colb = h * 64 + lq * 8;
    const size_t base = (size_t)b * L_SEQ * DMODEL;

    bf8 afr[4][2], bfr[4][2];
#pragma unroll
    for (int i = 0; i < 4; ++i)
#pragma unroll
        for (int kk = 0; kk < 2; ++kk) {
            afr[i][kk] = *(const bf8*)(qh + base + (size_t)(l0 + i * 16 + lr) * 512 + colb + kk * 32);
            bfr[i][kk] = *(const bf8*)(kh + base + (size_t)(m0 + i * 16 + lr) * 512 + colb + kk * 32);
        }

    f4 acc[4][4];
    const f4 zero = {0.f, 0.f, 0.f, 0.f};
#pragma unroll
    for (int mt = 0; mt < 4; ++mt)
#pragma unroll
        for (int nt = 0; nt < 4; ++nt) acc[mt][nt] = zero;

#pragma unroll
    for (int kk = 0; kk < 2; ++kk)
#pragma unroll
        for (int mt = 0; mt < 4; ++mt)
#pragma unroll
            for (int nt = 0; nt < 4; ++nt)
                acc[mt][nt] = __builtin_amdgcn_mfma_f32_16x16x32_bf16(
                    afr[mt][kk], bfr[nt][kk], acc[mt][nt], 0, 0, 0);

    float* out = sc + (size_t)z * L_SEQ * L_SEQ;
#pragma unroll
    for (int mt = 0; mt < 4; ++mt)
#pragma unroll
        for (int nt = 0; nt < 4; ++nt)
#pragma unroll
            for (int r = 0; r < 4; ++r)
                out[(size_t)(l0 + mt * 16 + lq * 4 + r) * 1024 + m0 + nt * 16 + lr] = acc[mt][nt][r];
}

// ---------------------------------------------------------------------------
// bias + mask + softmax, one block per (b,l), all 8 heads; in-place on attn.
// ---------------------------------------------------------------------------
__global__ __launch_bounds__(256) void bias_softmax_kernel(
    float* __restrict__ attn,
    const int* __restrict__ mask,
    const int* __restrict__ tf1, const int* __restrict__ tf2,
    const int* __restrict__ tf3, const int* __restrict__ tf4,
    const int* __restrict__ tf5,
    const float* __restrict__ emb1, const float* __restrict__ emb2,
    const float* __restrict__ emb3, const float* __restrict__ emb4,
    const float* __restrict__ emb5)
{
    const int l = blockIdx.x, b = blockIdx.y, t = threadIdx.x;
    __shared__ float embs[5][NHEAD][64];
    __shared__ float s[NHEAD][L_SEQ];
    __shared__ float rinv[NHEAD];

    {
        const float* es[5] = {emb1, emb2, emb3, emb4, emb5};
        for (int i = t; i < 5 * 512; i += 256) {
            int j = i >> 9, rem = i & 511;
            int h = rem >> 6, idx = rem & 63;
            embs[j][h][idx] = es[j][idx * NHEAD + h];
        }
    }
    __syncthreads();

    const size_t rowbase = ((size_t)(b * L_SEQ + l)) * L_SEQ;
#pragma unroll
    for (int c = 0; c < 4; ++c) {
        const int m = (c << 8) + t;
        const int am  = mask[rowbase + m];
        const int t1v = tf1[rowbase + m];
        float bias8[NHEAD];
        if (t1v >= 0) {
            const int i2 = tf2[rowbase + m];
            const int i3 = tf3[rowbase + m];
            const int i4 = tf4[rowbase + m];
            const int i5 = tf5[rowbase + m];
#pragma unroll
            for (int h = 0; h < NHEAD; ++h)
                bias8[h] = embs[0][h][t1v] + embs[1][h][i2] + embs[2][h][i3]
                         + embs[3][h][i4] + embs[4][h][i5];
        } else {
#pragma unroll
            for (int h = 0; h < NHEAD; ++h) bias8[h] = 0.f;
        }
#pragma unroll
        for (int h = 0; h < NHEAD; ++h) {
            const float raw = attn[(((size_t)(h * NB + b)) * L_SEQ + l) * L_SEQ + m];
            s[h][m] = am ? -INFINITY : (raw + bias8[h]) * 0.125f;
        }
    }
    __syncthreads();

    {
        const int h = t >> 5, i = t & 31;
        float mx = -INFINITY;
        for (int m = i; m < L_SEQ; m += 32) mx = fmaxf(mx, s[h][m]);
#pragma unroll
        for (int off = 16; off; off >>= 1) mx = fmaxf(mx, __shfl_down(mx, off, 32));
        mx = __shfl(mx, 0, 32);
        float sm = 0.f;
        for (int m = i; m < L_SEQ; m += 32) {
            float e = __expf(s[h][m] - mx);
            s[h][m] = e;
            sm += e;
        }
#pragma unroll
        for (int off = 16; off; off >>= 1) sm += __shfl_down(sm, off, 32);
        if (i == 0) rinv[h] = 1.0f / sm;
    }
    __syncthreads();

    float inv[NHEAD];
#pragma unroll
    for (int h = 0; h < NHEAD; ++h) inv[h] = rinv[h];
    for (int m = t; m < L_SEQ; m += 256) {
#pragma unroll
        for (int h = 0; h < NHEAD; ++h)
            attn[(((size_t)(h * NB + b)) * L_SEQ + l) * L_SEQ + m] = s[h][m] * inv[h];
    }
}

// ---------------------------------------------------------------------------
// AV GEMM: per z=h*2+b, pv[b,l,h*64+d] = sum_m attn[z,l,m] * vht[b,h*64+d,m]
// Block 256 thr = 4 waves; tile 128l x 64d; wave: 32l x 64d = 2x4 frags.
// attn read fp32, converted to bf16 in-register. Output pv bf16 natural.
// ---------------------------------------------------------------------------
__global__ __launch_bounds__(256) void av_mfma_kernel(
    const float* __restrict__ attn, const short* __restrict__ vht,
    short* __restrict__ pv)
{
    const int z = blockIdx.y, h = z >> 1, b = z & 1;
    const int w = threadIdx.x >> 6, lane = threadIdx.x & 63;
    const int lr = lane & 15, lq = lane >> 4;
    const int l0 = blockIdx.x * 128 + w * 32;
    const float* Ab = attn + (size_t)z * L_SEQ * L_SEQ;
    const short* Bb = vht + ((size_t)b * 512 + h * 64) * 1024;

    f4 acc[2][4];
    const f4 zero = {0.f, 0.f, 0.f, 0.f};
#pragma unroll
    for (int mt = 0; mt < 2; ++mt)
#pragma unroll
        for (int nt = 0; nt < 4; ++nt) acc[mt][nt] = zero;

    for (int k0 = 0; k0 < L_SEQ; k0 += 32) {
        bf8 a[2];
#pragma unroll
        for (int mt = 0; mt < 2; ++mt) {
            const float* p = Ab + (size_t)(l0 + mt * 16 + lr) * 1024 + k0 + lq * 8;
            float4 f0 = *(const float4*)p;
            float4 f1 = *(const float4*)(p + 4);
            bf8 tv;
            tv[0] = f2bf(f0.x); tv[1] = f2bf(f0.y); tv[2] = f2bf(f0.z); tv[3] = f2bf(f0.w);
            tv[4] = f2bf(f1.x); tv[5] = f2bf(f1.y); tv[6] = f2bf(f1.z); tv[7] = f2bf(f1.w);
            a[mt] = tv;
        }
#pragma unroll
        for (int nt = 0; nt < 4; ++nt) {
            bf8 bv = *(const bf8*)(Bb + (size_t)(nt * 16 + lr) * 1024 + k0 + lq * 8);
            acc[0][nt] = __builtin_amdgcn_mfma_f32_16x16x32_bf16(a[0], bv, acc[0][nt], 0, 0, 0);
            acc[1][nt] = __builtin_amdgcn_mfma_f32_16x16x32_bf16(a[1], bv, acc[1][nt], 0, 0, 0);
        }
    }

#pragma unroll
    for (int nt = 0; nt < 4; ++nt) {
        const int n = nt * 16 + lr;
#pragma unroll
        for (int mt = 0; mt < 2; ++mt) {
            const int rowb = l0 + mt * 16 + lq * 4;
#pragma unroll
            for (int r = 0; r < 4; ++r)
                pv[(size_t)(b * L_SEQ + rowb + r) * 512 + h * 64 + n] = f2bf(acc[mt][nt][r]);
        }
    }
}

// ---------------------------------------------------------------------------
// residual add + LayerNorm, one block per row
// ---------------------------------------------------------------------------
__global__ __launch_bounds__(256) void ln_kernel(
    const float* __restrict__ x, const float* __restrict__ res,
    const float* __restrict__ g, const float* __restrict__ bvec,
    float* __restrict__ out)
{
    const int row = blockIdx.x;
    const int t = threadIdx.x;
    float2 xv = ((const float2*)(x + (size_t)row * DMODEL))[t];
    float2 rv = ((const float2*)(res + (size_t)row * DMODEL))[t];
    const float a = xv.x + rv.x;
    const float c = xv.y + rv.y;
    float s = a + c, sq = a * a + c * c;
#pragma unroll
    for (int off = 32; off; off >>= 1) {
        s  += __shfl_down(s, off);
        sq += __shfl_down(sq, off);
    }
    __shared__ float ssum[4], ssq[4];
    __shared__ float smu, srs;
    const int wid = t >> 6, lane = t & 63;
    if (lane == 0) { ssum[wid] = s; ssq[wid] = sq; }
    __syncthreads();
    if (t == 0) {
        float ts = ssum[0] + ssum[1] + ssum[2] + ssum[3];
        float tq = ssq[0] + ssq[1] + ssq[2] + ssq[3];
        float mu = ts * (1.0f / DMODEL);
        float var = tq * (1.0f / DMODEL) - mu * mu;
        smu = mu;
        srs = rsqrtf(var + 1e-5f);
    }
    __syncthreads();
    const float mu = smu, rs = srs;
    float2 gv = ((const float2*)g)[t];
    float2 bv = ((const float2*)bvec)[t];
    float2 o;
    o.x = (a - mu) * rs * gv.x + bv.x;
    o.y = (c - mu) * rs * gv.y + bv.y;
    ((float2*)(out + (size_t)row * DMODEL))[t] = o;
}

extern "C" void kernel_launch(void* const* d_in, const int* in_sizes, int n_in,
                              void* d_out, int out_size, void* d_ws, size_t ws_size,
                              hipStream_t stream)
{
    const float* q    = (const float*)d_in[0];
    const float* k    = (const float*)d_in[1];
    const float* v    = (const float*)d_in[2];
    const int*   mask = (const int*)d_in[3];
    const int*   tf1  = (const int*)d_in[4];
    const int*   tf2  = (const int*)d_in[5];
    const int*   tf3  = (const int*)d_in[6];
    const int*   tf4  = (const int*)d_in[7];
    const int*   tf5  = (const int*)d_in[8];
    const float* w_q  = (const float*)d_in[9];
    const float* b_q  = (const float*)d_in[10];
    const float* w_k  = (const float*)d_in[11];
    const float* b_k  = (const float*)d_in[12];
    const float* w_v  = (const float*)d_in[13];
    const float* b_v  = (const float*)d_in[14];
    const float* emb1 = (const float*)d_in[15];
    const float* emb2 = (const float*)d_in[16];
    const float* emb3 = (const float*)d_in[17];
    const float* emb4 = (const float*)d_in[18];
    const float* emb5 = (const float*)d_in[19];
    const float* fc_w = (const float*)d_in[20];
    const float* fc_b = (const float*)d_in[21];
    const float* ln_g = (const float*)d_in[22];
    const float* ln_b = (const float*)d_in[23];

    float* out  = (float*)d_out;                       // [2048][512]
    float* attn = out + (size_t)NB * L_SEQ * DMODEL;   // [16][1024][1024]

    // ws layout (bytes): total exactly 20 MiB
    char* wsb = (char*)d_ws;
    short* qb   = (short*)(wsb + 0);                    // 2 MiB  [2048][512] bf16
    short* kb   = (short*)(wsb + (2u << 20));           // 2 MiB
    short* vb   = (short*)(wsb + (4u << 20));           // 2 MiB
    short* Wtq  = (short*)(wsb + (6u << 20));           // 0.5 MiB [512n][512k]
    short* Wtk  = (short*)(wsb + (6u << 20) + (512u << 10));
    short* Wtv  = (short*)(wsb + (7u << 20));
    short* Wtfc = (short*)(wsb + (7u << 20) + (512u << 10));
    short* qh   = (short*)(wsb + (8u << 20));           // 2 MiB [2048][512] bf16
    short* kh   = (short*)(wsb + (10u << 20));          // 2 MiB
    short* vht  = (short*)(wsb + (12u << 20));          // 2 MiB [2][512][1024] bf16
    short* pv   = (short*)(wsb + (14u << 20));          // 2 MiB [2048][512] bf16
    float* fco  = (float*)(wsb + (16u << 20));          // 4 MiB [2048][512] fp32

    const int n4 = NB * L_SEQ * DMODEL / 4;             // 262144

    cast_bf16_kernel<<<n4 / 256, 256, 0, stream>>>(q, qb, n4);
    cast_bf16_kernel<<<n4 / 256, 256, 0, stream>>>(k, kb, n4);
    cast_bf16_kernel<<<n4 / 256, 256, 0, stream>>>(v, vb, n4);

    transpose_cast_kernel<<<dim3(16, 16, 4), dim3(32, 8), 0, stream>>>(
        w_q, w_k, w_v, fc_w, Wtq, Wtk, Wtv, Wtfc);

    dim3 gproj(DMODEL / 64, NB * L_SEQ / 64);           // (8, 32)
    gemm_mfma_kernel<0><<<gproj, 256, 0, stream>>>(qb, Wtq, b_q, qh);
    gemm_mfma_kernel<0><<<gproj, 256, 0, stream>>>(kb, Wtk, b_k, kh);
    gemm_mfma_kernel<1><<<gproj, 256, 0, stream>>>(vb, Wtv, b_v, vht);

    scores_mfma_kernel<<<dim3(8, 8, 16), 256, 0, stream>>>(qh, kh, attn);

    bias_softmax_kernel<<<dim3(L_SEQ, NB), 256, 0, stream>>>(
        attn, mask, tf1, tf2, tf3, tf4, tf5, emb1, emb2, emb3, emb4, emb5);

    av_mfma_kernel<<<dim3(8, 16), 256, 0, stream>>>(attn, vht, pv);

    gemm_mfma_kernel<2><<<gproj, 256, 0, stream>>>(pv, Wtfc, fc_b, fco);

    ln_kernel<<<NB * L_SEQ, 256, 0, stream>>>(fco, q, ln_g, ln_b, out);
}